// Round 8
// baseline (1353.118 us; speedup 1.0000x reference)
//
#include <hip/hip_runtime.h>

// RRF2d: y[b,o,p] = sum_l patches[b,l,p] * W[o,l,p] + bias[o,p]
// B=32, C_IN=32, H=W=64, K=3 pad=1, C_OUT=64, L=4096, KL=288
//
// R8 = R7 staging skeleton + (a) halo via overlapping 16B x-loads (no
// bpermute), (b) o_tile=4 (FMA fraction ~75%, half the x re-reads).
// Block (64,8): 8 waves x 4 batches = all 32 b => weights leave HBM once.
// Thread tile: 2 cols (float2) x 4 o x 4 b. Grid 32 x 16 = 512 = 2/CU.
// Staging: CC=2 channels/chunk = 144 pieces of 64 floats, 18/wave,
// counted vmcnt(18) -> s_barrier (R4/R6/R7-proven ordering).
// LDS 2 x 36 KB = 72 KB.

#define C_IN   32
#define H_SZ   64
#define W_SZ   64
#define C_OUT  64
#define L_SZ   4096
#define KL     288
#define XCH    (H_SZ * W_SZ)
#define CC     2
#define NCHUNK (C_IN / CC)               // 16
#define WBUF   (CC * 9 * 4 * 128)        // 9216 floats = 36 KB per buffer

__device__ __forceinline__ void gload_lds4(const float* g, float* l) {
    __builtin_amdgcn_global_load_lds(
        (const __attribute__((address_space(1))) void*)g,
        (__attribute__((address_space(3))) void*)l, 4, 0, 0);
}

__global__ __launch_bounds__(512, 4)
void rrf2d_kernel(const float* __restrict__ x,
                  const float* __restrict__ wgt,
                  const float* __restrict__ bias,
                  float* __restrict__ out) {
    __shared__ float wlds[2][WBUF];      // 72 KB

    const int t   = threadIdx.x;                                  // 0..63
    const int wyu = __builtin_amdgcn_readfirstlane(threadIdx.y);  // 0..7
    const int rb  = t >> 5;
    const int k   = t & 31;
    const int c0  = k * 2;
    const int h0  = blockIdx.x * 2;
    const int o0  = blockIdx.y * 4;
    const int b0  = wyu * 4;
    const int h   = h0 + rb;
    const int p   = h * W_SZ + c0;
    const int pl  = rb * 64 + c0;        // p_local (0..127)
    const int p0  = h0 * W_SZ;

    // per-dh clamped tap rows + validity (per-lane: depends on rb)
    int roff[3]; float rvm[3];
    #pragma unroll
    for (int dh = 0; dh < 3; ++dh) {
        const int r = h + dh - 1;
        rvm[dh] = ((unsigned)r < (unsigned)H_SZ) ? 1.f : 0.f;
        const int rc = r < 0 ? 0 : (r > H_SZ - 1 ? H_SZ - 1 : r);
        roff[dh] = rc * W_SZ;
    }
    const bool edgeblk = (h0 == 0) || (h0 == H_SZ - 2);
    // overlapping halo load: cols loffc..loffc+3; lane classes fix ends
    const bool e0  = (k == 0);
    const bool e31 = (k == 31);
    const int  loffc = e0 ? 0 : (e31 ? 60 : c0 - 1);

    float2 acc[4][4];
    #pragma unroll
    for (int i = 0; i < 4; ++i)
        #pragma unroll
        for (int j = 0; j < 4; ++j) { acc[i][j].x = 0.f; acc[i][j].y = 0.f; }

    const size_t base0 = (size_t)o0 * (KL * (size_t)L_SZ) + p0;
    const size_t ostr  = (size_t)KL * L_SZ;

    // stage chunk ch (channels 2ch, 2ch+1) into wlds[ch&1].
    // 144 pieces of 64 floats; wave wyu takes r = wyu*18 + s.
    // r = ((cc*9+j)*4+o)*2 + q ; dst offset = r*64.
    auto stage = [&](int ch) {
        float* dst = wlds[ch & 1];
        const size_t coff = (size_t)ch * (CC * 9) * L_SZ;
        #pragma unroll
        for (int s = 0; s < 18; ++s) {
            const int r   = wyu * 18 + s;
            const int cc  = r / 72;
            const int rem = r % 72;
            const int j   = rem >> 3;
            const int o   = (rem >> 1) & 3;
            const int q   = rem & 1;
            const float* g = wgt + base0 + (size_t)o * ostr + coff
                           + (size_t)(cc * 9 + j) * L_SZ + q * 64 + t;
            gload_lds4(g, dst + r * 64);
        }
    };

    // prologue
    stage(0);
    asm volatile("s_waitcnt vmcnt(0)" ::: "memory");
    __builtin_amdgcn_s_barrier();

    for (int ch = 0; ch < NCHUNK; ++ch) {
        if (ch + 1 < NCHUNK) {
            stage(ch + 1);
            asm volatile("s_waitcnt vmcnt(18)" ::: "memory");
        } else {
            asm volatile("s_waitcnt vmcnt(0)" ::: "memory");
        }
        __builtin_amdgcn_s_barrier();

        const float* wbc = wlds[ch & 1];

        #pragma unroll
        for (int cc = 0; cc < CC; ++cc) {
            const int c = ch * CC + cc;
            const float* wb  = wbc + cc * (9 * 4 * 128);
            const float* xco = x + (size_t)c * XCH;

            #pragma unroll
            for (int dh = 0; dh < 3; ++dh) {
                // weights: 3 dw x 4 o float2 from LDS
                float2 wv[3][4];
                #pragma unroll
                for (int dw = 0; dw < 3; ++dw) {
                    const int j = dh * 3 + dw;
                    #pragma unroll
                    for (int o = 0; o < 4; ++o)
                        wv[dw][o] = *(const float2*)(wb + (j * 4 + o) * 128 + pl);
                }

                // x taps: one overlapping 16B load per b, ends fixed by selects
                float xs[4][4];
                #pragma unroll
                for (int i = 0; i < 4; ++i) {
                    const float* xp = xco + (size_t)(b0 + i) * (C_IN * XCH)
                                    + roff[dh] + loffc;
                    float4 v;
                    __builtin_memcpy(&v, xp, 16);   // dword-aligned dwordx4
                    float s0 = e31 ? v.y : v.x;
                    float s1 = e31 ? v.z : v.y;
                    float s2 = e31 ? v.w : v.z;
                    float s3 = e31 ? 0.f : v.w;
                    s0 = e0 ? 0.f : s0;
                    s1 = e0 ? v.x : s1;
                    s2 = e0 ? v.y : s2;
                    s3 = e0 ? v.z : s3;
                    if (edgeblk) {                  // block-uniform branch
                        s0 *= rvm[dh]; s1 *= rvm[dh];
                        s2 *= rvm[dh]; s3 *= rvm[dh];
                    }
                    xs[i][0] = s0; xs[i][1] = s1; xs[i][2] = s2; xs[i][3] = s3;
                }

                // 4b x 3dw x 4o x 2col = 96 FMAs
                #pragma unroll
                for (int i = 0; i < 4; ++i)
                    #pragma unroll
                    for (int dw = 0; dw < 3; ++dw)
                        #pragma unroll
                        for (int o = 0; o < 4; ++o) {
                            acc[i][o].x = fmaf(xs[i][dw],     wv[dw][o].x, acc[i][o].x);
                            acc[i][o].y = fmaf(xs[i][dw + 1], wv[dw][o].y, acc[i][o].y);
                        }
            }
        }
        __builtin_amdgcn_s_barrier();    // wlds[ch&1] reads done before overwrite
    }

    #pragma unroll
    for (int o = 0; o < 4; ++o) {
        const float2 bv = *(const float2*)(bias + (size_t)(o0 + o) * L_SZ + p);
        #pragma unroll
        for (int i = 0; i < 4; ++i) {
            float2 r;
            r.x = acc[i][o].x + bv.x;
            r.y = acc[i][o].y + bv.y;
            *(float2*)(out + ((size_t)(b0 + i) * C_OUT + (o0 + o)) * L_SZ + p) = r;
        }
    }
}

extern "C" void kernel_launch(void* const* d_in, const int* in_sizes, int n_in,
                              void* d_out, int out_size, void* d_ws, size_t ws_size,
                              hipStream_t stream) {
    const float* x    = (const float*)d_in[0];
    const float* wgt  = (const float*)d_in[1];
    const float* bias = (const float*)d_in[2];
    float* out        = (float*)d_out;

    dim3 block(64, 8);                    // 8 waves = 8 b-chunks of 4
    dim3 grid(H_SZ / 2, C_OUT / 4);       // 512 blocks = 2/CU

    hipLaunchKernelGGL(rrf2d_kernel, grid, block, 0, stream, x, wgt, bias, out);
}